// Round 1
// baseline (5996.787 us; speedup 1.0000x reference)
//
#include <hip/hip_runtime.h>
#include <cstdint>

// ---------- types / helpers ----------
typedef __attribute__((ext_vector_type(8))) short short8;   // 8 x bf16 (4 VGPRs)
typedef __attribute__((ext_vector_type(4))) float f32x4;
typedef unsigned short us16;

#define DEV __device__ __forceinline__

DEV us16 f2bf(float f){
  union { float f; unsigned u; } v; v.f = f;
  unsigned r = (v.u + 0x7FFFu + ((v.u >> 16) & 1u)) >> 16;   // RNE
  return (us16)r;
}
DEV float bf2f(us16 h){
  union { unsigned u; float f; } v; v.u = ((unsigned)h) << 16;
  return v.f;
}
DEV float fsig(float x){              // 1/(1+e^-x)
  float e = __builtin_amdgcn_exp2f(-1.4426950408889634f * x);
  return __builtin_amdgcn_rcpf(1.0f + e);
}
DEV float ftanh(float x){             // 2/(1+e^-2x) - 1
  float e = __builtin_amdgcn_exp2f(-2.8853900817779268f * x);
  return fmaf(2.0f, __builtin_amdgcn_rcpf(1.0f + e), -1.0f);
}
DEV float fsoftplus(float x){         // max(x,0) + ln(1+e^-|x|)
  float ax = fabsf(x);
  float e = __builtin_amdgcn_exp2f(-1.4426950408889634f * ax);
  float l = 0.69314718055994531f * __builtin_amdgcn_logf(1.0f + e);
  return fmaxf(x, 0.0f) + l;
}
DEV f32x4 mfma16(short8 a, short8 b, f32x4 c){
  return __builtin_amdgcn_mfma_f32_16x16x32_bf16(a, b, c, 0, 0, 0);
}

// Dims
// B=256, T=WN=200, hidden half HH=256, gates=1024, V=128, CD=30, WD=128, K=12
// MFMA fragment layouts (HW-verified per guide):
//   A: lane L holds A[m=L&15][k=(L>>4)*8+j]
//   B: lane L holds B[k=(L>>4)*8+j][n=L&15]   (i.e. B^T rows, k-contiguous)
//   D: lane L reg r holds D[row=(L>>4)*4+r][col=L&15]

// ---------- preprocessing kernels ----------

// char_vec[b][t][0..31] = bf16(char_emb[characters[b][t]][c]), pad c=30,31 -> 0
__global__ void k_embed(const int* __restrict__ chars, const float* __restrict__ emb,
                        us16* __restrict__ out){
  int tid = blockIdx.x * 256 + threadIdx.x;          // 256*200*32
  if (tid >= 256*200*32) return;
  int c = tid & 31, bt = tid >> 5;
  int idx = chars[bt];
  float v = (c < 30) ? emb[idx * 30 + c] : 0.0f;
  out[tid] = f2bf(v);
}

__global__ void k_cvt(const float* __restrict__ src, us16* __restrict__ dst, int n){
  int tid = blockIdx.x * 256 + threadIdx.x;
  if (tid < n) dst[tid] = f2bf(src[tid]);
}

// LSTM combined weight [Whh | Wih], gate rows reordered per (wave, ntile),
// stored in MFMA-B fragment order: [w(4)][nt(16)][kc(KC)][lane(64) x 8bf16]
__global__ void k_swz_lstm(const float* __restrict__ Whh, const float* __restrict__ Wih,
                           int I, int KC, us16* __restrict__ dst){
  int tid = blockIdx.x * 256 + threadIdx.x;
  int total = 4 * 16 * KC * 512;
  if (tid >= total) return;
  int e = tid & 511, chunk = tid >> 9;
  int L = e >> 3, j = e & 7;
  int kc = chunk % KC; int rem = chunk / KC;
  int nt = rem & 15, w = rem >> 4;
  int gt = nt >> 2, s = nt & 3;
  int g = gt * 256 + w * 64 + s * 16 + (L & 15);     // gate row
  int k = kc * 32 + (L >> 4) * 8 + j;                // k index ([h|x])
  float v = 0.0f;
  if (k < 256) v = Whh[g * 256 + k];
  else if (k - 256 < I) v = Wih[g * I + (k - 256)];
  dst[tid] = f2bf(v);
}

// FF weight swizzle: [ntile(NT)][kc(KC)][lane x 8], zero-padded past N/K
__global__ void k_swz_ff(const float* __restrict__ W, int N, int Kd, int KC,
                         us16* __restrict__ dst, int total){
  int tid = blockIdx.x * 256 + threadIdx.x;
  if (tid >= total) return;
  int e = tid & 511, chunk = tid >> 9;
  int L = e >> 3, j = e & 7;
  int kc = chunk % KC; int nt = chunk / KC;
  int g = nt * 16 + (L & 15);
  int k = kc * 32 + (L >> 4) * 8 + j;
  float v = (g < N && k < Kd) ? W[g * Kd + k] : 0.0f;
  dst[tid] = f2bf(v);
}

// zero the k-padding columns 712..735 of x_cat
__global__ void k_zpad(us16* __restrict__ xcat){
  int tid = blockIdx.x * 256 + threadIdx.x;          // 51200*24
  if (tid >= 51200 * 24) return;
  int r = tid / 24, c = tid - r * 24;
  xcat[r * 736 + 712 + c] = 0;
}

// ---------- bidirectional LSTM, all 4 directions in one launch ----------
// grid = 32: dir = blockIdx>>3 (0 cf,1 cb,2 wf,3 wb), slice = blockIdx&7 (32 batch rows)
// Per block: full hidden state for its slice lives in LDS (h, bf16) + VGPRs (c, fp32);
// only __syncthreads needed. W streamed from L2 in fragment order.
__global__ __launch_bounds__(256, 1) void k_lstm(
    const us16* __restrict__ char_vec, const us16* __restrict__ words_bf,
    const us16* __restrict__ wsw_cf, const us16* __restrict__ wsw_cb,
    const us16* __restrict__ wsw_wf, const us16* __restrict__ wsw_wb,
    const float* __restrict__ b_cf, const float* __restrict__ b_cb,
    const float* __restrict__ b_wf, const float* __restrict__ b_wb,
    const int* __restrict__ len_char, const int* __restrict__ len_word,
    us16* __restrict__ h_char, us16* __restrict__ h_word)
{
  const int dir   = blockIdx.x >> 3;
  const int slice = blockIdx.x & 7;
  const bool isChar = dir < 2;
  const bool rev    = dir & 1;
  const int KC   = isChar ? 9 : 12;       // k-chunks of 32 (K = 288 / 384)
  const int Sa   = isChar ? 296 : 392;    // LDS row stride (bf16): 148/196 dw -> <=2-way banks
  const int xdim = isChar ? 32 : 128;
  const int xsh  = isChar ? 2 : 4;        // log2(xdim/8)
  const us16* Wsw  = (dir == 0) ? wsw_cf : (dir == 1) ? wsw_cb : (dir == 2) ? wsw_wf : wsw_wb;
  const float* bias= (dir == 0) ? b_cf  : (dir == 1) ? b_cb  : (dir == 2) ? b_wf  : b_wb;
  const us16* xbuf = isChar ? char_vec : words_bf;
  us16* hout       = isChar ? h_char : h_word;
  const int hcol0  = rev ? 256 : 0;
  const int* lens  = isChar ? len_char : len_word;
  const int b0 = slice * 32;

  const int tid = threadIdx.x;
  const int w = tid >> 6, L = tid & 63;
  const int lrow = L & 15, lq = L >> 4;

  __shared__ us16 abuf[32 * 392];          // [32 batch rows][Sa]: cols 0..255 h, 256.. x

  for (int e = tid; e < 32 * 256; e += 256) abuf[(e >> 8) * Sa + (e & 255)] = 0;

  float bv[4][4];                          // bias per (gate type, strip)
  #pragma unroll
  for (int gt = 0; gt < 4; ++gt)
    #pragma unroll
    for (int s = 0; s < 4; ++s)
      bv[gt][s] = bias[gt * 256 + w * 64 + s * 16 + lrow];

  int lenv[2][4];
  #pragma unroll
  for (int m0 = 0; m0 < 2; ++m0)
    #pragma unroll
    for (int r = 0; r < 4; ++r)
      lenv[m0][r] = lens[b0 + m0 * 16 + lq * 4 + r];

  float cst[2][4][4];                      // c state: [m0][strip s][r], fp32
  #pragma unroll
  for (int m0 = 0; m0 < 2; ++m0)
    #pragma unroll
    for (int s = 0; s < 4; ++s)
      #pragma unroll
      for (int r = 0; r < 4; ++r) cst[m0][s][r] = 0.0f;

  const int nch = (32 * xdim) >> 3;
  const int cmask = (xdim >> 3) - 1;
  auto load_x = [&](int t){
    for (int ch = tid; ch < nch; ch += 256){
      int r = ch >> xsh;
      int c8 = (ch & cmask) << 3;
      *(short8*)&abuf[r * Sa + 256 + c8] =
        *(const short8*)&xbuf[((b0 + r) * 200 + t) * xdim + c8];
    }
  };
  load_x(rev ? 199 : 0);
  __syncthreads();

  const short8* WswV = (const short8*)Wsw;

  for (int tau = 0; tau < 200; ++tau){
    const int t = rev ? (199 - tau) : tau;
    f32x4 acc[4][4][2] = {};               // [gate type][strip][m0]
    for (int kc = 0; kc < KC; ++kc){
      short8 af0 = *(const short8*)&abuf[lrow * Sa + kc * 32 + lq * 8];
      short8 af1 = *(const short8*)&abuf[(16 + lrow) * Sa + kc * 32 + lq * 8];
      #pragma unroll
      for (int nt = 0; nt < 16; ++nt){
        short8 bf = WswV[((w * 16 + nt) * KC + kc) * 64 + L];
        acc[nt >> 2][nt & 3][0] = mfma16(af0, bf, acc[nt >> 2][nt & 3][0]);
        acc[nt >> 2][nt & 3][1] = mfma16(af1, bf, acc[nt >> 2][nt & 3][1]);
      }
    }
    __syncthreads();                       // all LDS reads of h/x for step t done
    #pragma unroll
    for (int m0 = 0; m0 < 2; ++m0){
      #pragma unroll
      for (int r = 0; r < 4; ++r){
        const int bm = m0 * 16 + lq * 4 + r;
        const bool mk = t < lenv[m0][r];
        const long gbase = ((long)(b0 + bm) * 200 + t) * 512 + hcol0;
        #pragma unroll
        for (int s = 0; s < 4; ++s){
          float gi = acc[0][s][m0][r] + bv[0][s];
          float gf = acc[1][s][m0][r] + bv[1][s];
          float gg = acc[2][s][m0][r] + bv[2][s];
          float go = acc[3][s][m0][r] + bv[3][s];
          float co = cst[m0][s][r];
          float cn = fsig(gf) * co + fsig(gi) * ftanh(gg);
          float hn = fsig(go) * ftanh(cn);
          const int col = w * 64 + s * 16 + lrow;
          if (mk){
            cst[m0][s][r] = cn;
            us16 hb = f2bf(hn);
            abuf[bm * Sa + col] = hb;      // state for next step
            hout[gbase + col] = hb;        // masked output = hn
          } else {
            hout[gbase + col] = 0;         // masked output = 0; state kept
          }
        }
      }
    }
    if (tau < 199) load_x(rev ? (198 - tau) : (tau + 1));
    __syncthreads();
  }
}

// ---------- generic FF GEMM: out = softplus(A[M,K]bf16 @ Wsw^T + bias) ----------
// grid = (M/128, ceil(N/128)); block 256 (4 waves). Wave w: rows w*32..+32, 8 n-tiles.
__global__ __launch_bounds__(256) void k_gemm(
    const us16* __restrict__ A, int KC, const us16* __restrict__ Wsw,
    const float* __restrict__ bias, int N,
    void* __restrict__ outp, int ostride, int ocol0, int out_f32)
{
  const int tid = threadIdx.x;
  const int w = tid >> 6, L = tid & 63;
  const int lrow = L & 15, lq = L >> 4;
  const int m0base = blockIdx.x * 128;
  const int ntbase = blockIdx.y * 8;
  const int Kd = KC * 32;
  __shared__ us16 At[128 * 40];            // 20 dw stride -> <=2-way banks
  f32x4 acc[8][2] = {};
  const short8* WswV = (const short8*)Wsw;
  const int srow = tid >> 1, scol = (tid & 1) * 16;

  for (int kc = 0; kc < KC; ++kc){
    const long abase = (long)(m0base + srow) * Kd + kc * 32 + scol;
    short8 v0 = *(const short8*)&A[abase];
    short8 v1 = *(const short8*)&A[abase + 8];
    *(short8*)&At[srow * 40 + scol] = v0;
    *(short8*)&At[srow * 40 + scol + 8] = v1;
    __syncthreads();
    short8 af0 = *(const short8*)&At[(w * 32 + lrow) * 40 + lq * 8];
    short8 af1 = *(const short8*)&At[(w * 32 + 16 + lrow) * 40 + lq * 8];
    #pragma unroll
    for (int nt = 0; nt < 8; ++nt){
      short8 bf = WswV[((ntbase + nt) * KC + kc) * 64 + L];
      acc[nt][0] = mfma16(af0, bf, acc[nt][0]);
      acc[nt][1] = mfma16(af1, bf, acc[nt][1]);
    }
    __syncthreads();
  }
  #pragma unroll
  for (int nt = 0; nt < 8; ++nt){
    const int col = (ntbase + nt) * 16 + lrow;
    if (col >= N) continue;
    const float bvv = bias[col];
    #pragma unroll
    for (int m0 = 0; m0 < 2; ++m0){
      #pragma unroll
      for (int r = 0; r < 4; ++r){
        float v = fsoftplus(acc[nt][m0][r] + bvv);
        const int row = m0base + w * 32 + m0 * 16 + lq * 4 + r;
        if (out_f32) ((float*)outp)[(long)row * ostride + ocol0 + col] = v;
        else         ((us16*)outp)[(long)row * ostride + ocol0 + col] = f2bf(v);
      }
    }
  }
}

// ---------- CRF NLL: one wave per batch row ----------
__global__ void k_crf(const float* __restrict__ logits, const int* __restrict__ tags,
                      const int* __restrict__ lens, const float* __restrict__ trans,
                      float* __restrict__ nll)
{
  const int b = blockIdx.x;
  const int lane = threadIdx.x;            // 64
  __shared__ float alpha[12];
  __shared__ float tmp[12];
  float tcol[12];
  if (lane < 12){
    #pragma unroll
    for (int i = 0; i < 12; ++i) tcol[i] = trans[i * 12 + lane];
    alpha[lane] = 0.0f;
  }
  const int len = lens[b];
  __syncthreads();
  for (int t = 0; t < len; ++t){
    float an = 0.0f;
    if (lane < 12){
      float mx = -3.0e38f;
      #pragma unroll
      for (int i = 0; i < 12; ++i) mx = fmaxf(mx, alpha[i] + tcol[i]);
      float ss = 0.0f;
      #pragma unroll
      for (int i = 0; i < 12; ++i)
        ss += __builtin_amdgcn_exp2f(1.4426950408889634f * (alpha[i] + tcol[i] - mx));
      an = logits[((long)b * 200 + t) * 12 + lane] + mx
         + 0.69314718055994531f * __builtin_amdgcn_logf(ss);
    }
    __syncthreads();
    if (lane < 12) alpha[lane] = an;
    __syncthreads();
  }
  if (lane < 12) tmp[lane] = alpha[lane] + trans[lane * 12 + 11];   // + trans[:,STOP]
  __syncthreads();
  // real path score, lanes stride over t
  float rs = 0.0f;
  for (int t = lane; t < len; t += 64){
    int tg = tags[b * 200 + t];
    int pv = (t == 0) ? 10 : tags[b * 200 + t - 1];                 // START=10
    rs += logits[((long)b * 200 + t) * 12 + tg] + trans[pv * 12 + tg];
  }
  #pragma unroll
  for (int off = 32; off > 0; off >>= 1) rs += __shfl_down(rs, off, 64);
  if (lane == 0){
    float mx = -3.0e38f;
    for (int i = 0; i < 12; ++i) mx = fmaxf(mx, tmp[i]);
    float ss = 0.0f;
    for (int i = 0; i < 12; ++i)
      ss += __builtin_amdgcn_exp2f(1.4426950408889634f * (tmp[i] - mx));
    float total = mx + 0.69314718055994531f * __builtin_amdgcn_logf(ss);
    rs += trans[tags[b * 200 + len - 1] * 12 + 11];                 // trans[last, STOP]
    nll[b] = total - rs;
  }
}

__global__ void k_sum(const float* __restrict__ nll, float* __restrict__ out){
  __shared__ float red[256];
  int t = threadIdx.x;
  red[t] = nll[t];
  __syncthreads();
  for (int s = 128; s > 0; s >>= 1){
    if (t < s) red[t] += red[t + s];
    __syncthreads();
  }
  if (t == 0) out[0] = red[0];
}

// ---------- launcher ----------
extern "C" void kernel_launch(void* const* d_in, const int* in_sizes, int n_in,
                              void* d_out, int out_size, void* d_ws, size_t ws_size,
                              hipStream_t stream)
{
  (void)in_sizes; (void)n_in; (void)out_size; (void)ws_size;
  const int*   characters = (const int*)  d_in[0];
  const float* words      = (const float*)d_in[1];
  const int*   tags       = (const int*)  d_in[2];
  const int*   len_char   = (const int*)  d_in[3];
  const int*   len_word   = (const int*)  d_in[4];
  const float* char_emb   = (const float*)d_in[5];
  const float* char_Wih_f = (const float*)d_in[6];
  const float* char_Whh_f = (const float*)d_in[7];
  const float* char_b_f   = (const float*)d_in[8];
  const float* char_Wih_b = (const float*)d_in[9];
  const float* char_Whh_b = (const float*)d_in[10];
  const float* char_b_b   = (const float*)d_in[11];
  const float* char_lin_W = (const float*)d_in[12];
  const float* char_lin_b = (const float*)d_in[13];
  const float* word_Wih_f = (const float*)d_in[14];
  const float* word_Whh_f = (const float*)d_in[15];
  const float* word_b_f   = (const float*)d_in[16];
  const float* word_Wih_b = (const float*)d_in[17];
  const float* word_Whh_b = (const float*)d_in[18];
  const float* word_b_b   = (const float*)d_in[19];
  const float* word_lin_W = (const float*)d_in[20];
  const float* word_lin_b = (const float*)d_in[21];
  const float* lin1_W     = (const float*)d_in[22];
  const float* lin1_b     = (const float*)d_in[23];
  const float* lin2_W     = (const float*)d_in[24];
  const float* lin2_b     = (const float*)d_in[25];
  const float* tag_W      = (const float*)d_in[26];
  const float* tag_b      = (const float*)d_in[27];
  const float* trans      = (const float*)d_in[28];

  char* ws = (char*)d_ws;
  size_t off = 0;
  auto take = [&](size_t bytes) -> char* {
    char* p = ws + off;
    off = (off + bytes + 511) & ~(size_t)511;
    return p;
  };
  us16* char_vec = (us16*)take((size_t)256*200*32*2);      //  3.1 MB
  us16* words_bf = (us16*)take((size_t)256*200*128*2);     // 12.5 MB
  us16* h_char   = (us16*)take((size_t)51200*512*2);       // 50 MB
  us16* h_word   = (us16*)take((size_t)51200*512*2);       // 50 MB
  us16* x_cat    = (us16*)take((size_t)51200*736*2);       // 71.9 MB
  us16* wsw_cf   = (us16*)take((size_t)4*16*9*512*2);
  us16* wsw_cb   = (us16*)take((size_t)4*16*9*512*2);
  us16* wsw_wf   = (us16*)take((size_t)4*16*12*512*2);
  us16* wsw_wb   = (us16*)take((size_t)4*16*12*512*2);
  us16* wswg1    = (us16*)take((size_t)32*16*512*2);
  us16* wswg2    = (us16*)take((size_t)16*16*512*2);
  us16* wswg3    = (us16*)take((size_t)32*23*512*2);
  us16* wswg4    = (us16*)take((size_t)16*16*512*2);
  us16* wswg5    = (us16*)take((size_t)8*8*512*2);
  float* logits  = (float*)take((size_t)51200*12*4);
  float* nll     = (float*)take((size_t)256*4);
  us16* x1 = h_char;   // dead after G1
  us16* x2 = h_word;   // dead after G2

  // preprocessing
  k_embed<<<6400, 256, 0, stream>>>(characters, char_emb, char_vec);
  k_cvt<<<(256*200*128 + 255)/256, 256, 0, stream>>>(words, words_bf, 256*200*128);
  k_swz_lstm<<<(4*16*9*512 + 255)/256, 256, 0, stream>>>(char_Whh_f, char_Wih_f, 30, 9, wsw_cf);
  k_swz_lstm<<<(4*16*9*512 + 255)/256, 256, 0, stream>>>(char_Whh_b, char_Wih_b, 30, 9, wsw_cb);
  k_swz_lstm<<<(4*16*12*512 + 255)/256, 256, 0, stream>>>(word_Whh_f, word_Wih_f, 128, 12, wsw_wf);
  k_swz_lstm<<<(4*16*12*512 + 255)/256, 256, 0, stream>>>(word_Whh_b, word_Wih_b, 128, 12, wsw_wb);
  k_swz_ff<<<(32*16*512 + 255)/256, 256, 0, stream>>>(char_lin_W, 512, 512, 16, wswg1, 32*16*512);
  k_swz_ff<<<(16*16*512 + 255)/256, 256, 0, stream>>>(word_lin_W, 200, 512, 16, wswg2, 16*16*512);
  k_swz_ff<<<(32*23*512 + 255)/256, 256, 0, stream>>>(lin1_W, 512, 712, 23, wswg3, 32*23*512);
  k_swz_ff<<<(16*16*512 + 255)/256, 256, 0, stream>>>(lin2_W, 256, 512, 16, wswg4, 16*16*512);
  k_swz_ff<<<(8*8*512 + 255)/256, 256, 0, stream>>>(tag_W, 12, 256, 8, wswg5, 8*8*512);
  k_zpad<<<4800, 256, 0, stream>>>(x_cat);

  // recurrences (4 directions concurrent in one launch)
  k_lstm<<<32, 256, 0, stream>>>(char_vec, words_bf, wsw_cf, wsw_cb, wsw_wf, wsw_wb,
                                 char_b_f, char_b_b, word_b_f, word_b_b,
                                 len_char, len_word, h_char, h_word);

  // feed-forward chain
  k_gemm<<<dim3(400, 4), 256, 0, stream>>>(h_char, 16, wswg1, char_lin_b, 512, x_cat, 736,   0, 0);
  k_gemm<<<dim3(400, 2), 256, 0, stream>>>(h_word, 16, wswg2, word_lin_b, 200, x_cat, 736, 512, 0);
  k_gemm<<<dim3(400, 4), 256, 0, stream>>>(x_cat, 23, wswg3, lin1_b, 512, x1, 512, 0, 0);
  k_gemm<<<dim3(400, 2), 256, 0, stream>>>(x1,    16, wswg4, lin2_b, 256, x2, 256, 0, 0);
  k_gemm<<<dim3(400, 1), 256, 0, stream>>>(x2,     8, wswg5, tag_b,   12, logits, 12, 0, 1);

  // CRF
  k_crf<<<256, 64, 0, stream>>>(logits, tags, len_char, trans, nll);
  k_sum<<<1, 256, 0, stream>>>(nll, (float*)d_out);
}

// Round 2
// 2097.043 us; speedup vs baseline: 2.8596x; 2.8596x over previous
//
#include <hip/hip_runtime.h>
#include <cstdint>

// ---------- types / helpers ----------
typedef __attribute__((ext_vector_type(8))) short short8;   // 8 x bf16 (4 VGPRs)
typedef __attribute__((ext_vector_type(4))) float f32x4;
typedef unsigned short us16;

#define DEV __device__ __forceinline__

DEV us16 f2bf(float f){
  union { float f; unsigned u; } v; v.f = f;
  unsigned r = (v.u + 0x7FFFu + ((v.u >> 16) & 1u)) >> 16;   // RNE
  return (us16)r;
}
DEV float fsig(float x){              // 1/(1+e^-x)
  float e = __builtin_amdgcn_exp2f(-1.4426950408889634f * x);
  return __builtin_amdgcn_rcpf(1.0f + e);
}
DEV float ftanh(float x){             // 2/(1+e^-2x) - 1
  float e = __builtin_amdgcn_exp2f(-2.8853900817779268f * x);
  return fmaf(2.0f, __builtin_amdgcn_rcpf(1.0f + e), -1.0f);
}
DEV float fsoftplus(float x){         // max(x,0) + ln(1+e^-|x|)
  float ax = fabsf(x);
  float e = __builtin_amdgcn_exp2f(-1.4426950408889634f * ax);
  float l = 0.69314718055994531f * __builtin_amdgcn_logf(1.0f + e);
  return fmaxf(x, 0.0f) + l;
}
DEV f32x4 mfma16(short8 a, short8 b, f32x4 c){
  return __builtin_amdgcn_mfma_f32_16x16x32_bf16(a, b, c, 0, 0, 0);
}

// Dims: B=256, T=WN=200, HH=256 (per direction), gates=1024, K(tags)=12
// MFMA fragment layouts (HW-verified per guide):
//   A: lane L holds A[m=L&15][k=(L>>4)*8+j]
//   B: lane L holds B[k=(L>>4)*8+j][n=L&15]
//   D: lane L reg r holds D[row=(L>>4)*4+r][col=L&15]

// ---------- preprocessing kernels ----------

__global__ void k_embed(const int* __restrict__ chars, const float* __restrict__ emb,
                        us16* __restrict__ out){
  int tid = blockIdx.x * 256 + threadIdx.x;          // 256*200*32
  if (tid >= 256*200*32) return;
  int c = tid & 31, bt = tid >> 5;
  int idx = chars[bt];
  float v = (c < 30) ? emb[idx * 30 + c] : 0.0f;
  out[tid] = f2bf(v);
}

__global__ void k_cvt(const float* __restrict__ src, us16* __restrict__ dst, int n){
  int tid = blockIdx.x * 256 + threadIdx.x;
  if (tid < n) dst[tid] = f2bf(src[tid]);
}

// LSTM combined weight [Whh | Wih], rows reordered for 16-wave blocks:
// layout [w(16)][gt(4)][kc(KC)][lane(64) x 8bf16]; gate row = gt*256 + w*16 + lrow
__global__ void k_swz_lstm(const float* __restrict__ Whh, const float* __restrict__ Wih,
                           int I, int KC, us16* __restrict__ dst){
  int tid = blockIdx.x * 256 + threadIdx.x;
  int total = 64 * KC * 512;
  if (tid >= total) return;
  int e = tid & 511, chunk = tid >> 9;
  int L = e >> 3, j = e & 7;
  int kc = chunk % KC; int rem = chunk / KC;
  int gt = rem & 3, w = rem >> 2;
  int g = gt * 256 + w * 16 + (L & 15);              // gate row
  int k = kc * 32 + (L >> 4) * 8 + j;                // k index ([h|x])
  float v = 0.0f;
  if (k < 256) v = Whh[g * 256 + k];
  else if (k - 256 < I) v = Wih[g * I + (k - 256)];
  dst[tid] = f2bf(v);
}

// FF weight swizzle: [ntile(NT)][kc(KC)][lane x 8], zero-padded past N/K
__global__ void k_swz_ff(const float* __restrict__ W, int N, int Kd, int KC,
                         us16* __restrict__ dst, int total){
  int tid = blockIdx.x * 256 + threadIdx.x;
  if (tid >= total) return;
  int e = tid & 511, chunk = tid >> 9;
  int L = e >> 3, j = e & 7;
  int kc = chunk % KC; int nt = chunk / KC;
  int g = nt * 16 + (L & 15);
  int k = kc * 32 + (L >> 4) * 8 + j;
  float v = (g < N && k < Kd) ? W[g * Kd + k] : 0.0f;
  dst[tid] = f2bf(v);
}

// zero the k-padding columns 712..735 of x_cat
__global__ void k_zpad(us16* __restrict__ xcat){
  int tid = blockIdx.x * 256 + threadIdx.x;          // 51200*24
  if (tid >= 51200 * 24) return;
  int r = tid / 24, c = tid - r * 24;
  xcat[r * 736 + 712 + c] = 0;
}

// ---------- bidirectional LSTM ----------
// grid = 32 blocks x 1024 threads (16 waves, 4/SIMD for latency hiding).
// dir = blockIdx>>3 (0 cf,1 cb,2 wf,3 wb), slice = blockIdx&7 (32 batch rows).
// Wave w owns h-column strip [w*16, w*16+16): computes all 4 gate types for it,
// so the LSTM cell epilogue is wave-local. h round-trips via LDS; c in VGPRs.
template<int KC, int XDIM, int SA>
DEV void lstm_body(us16* abuf, const us16* __restrict__ xbuf,
                   const us16* __restrict__ Wsw, const float* __restrict__ bias,
                   const int* __restrict__ lens, us16* __restrict__ hout,
                   int b0, int hcol0, bool rev)
{
  const int tid = threadIdx.x;
  const int w = tid >> 6, L = tid & 63;
  const int lrow = L & 15, lq = L >> 4;

  for (int e = tid; e < 32 * 256; e += 1024) abuf[(e >> 8) * SA + (e & 255)] = 0;

  float bv[4];
  #pragma unroll
  for (int gt = 0; gt < 4; ++gt) bv[gt] = bias[gt * 256 + w * 16 + lrow];

  int lenv[2][4];
  #pragma unroll
  for (int m0 = 0; m0 < 2; ++m0)
    #pragma unroll
    for (int r = 0; r < 4; ++r)
      lenv[m0][r] = lens[b0 + m0 * 16 + lq * 4 + r];

  float cst[2][4];
  #pragma unroll
  for (int m0 = 0; m0 < 2; ++m0)
    #pragma unroll
    for (int r = 0; r < 4; ++r) cst[m0][r] = 0.0f;

  const int nch = (32 * XDIM) >> 3;
  auto load_x = [&](int t){
    for (int ch = tid; ch < nch; ch += 1024){
      int r = ch / (XDIM >> 3);
      int c8 = (ch % (XDIM >> 3)) << 3;
      *(short8*)&abuf[r * SA + 256 + c8] =
        *(const short8*)&xbuf[((b0 + r) * 200 + t) * XDIM + c8];
    }
  };
  load_x(rev ? 199 : 0);
  __syncthreads();

  const short8* WswV = (const short8*)Wsw;

  for (int tau = 0; tau < 200; ++tau){
    const int t = rev ? (199 - tau) : tau;
    f32x4 acc[4][2] = {};                // [gate type][m-tile]
    #pragma unroll 3
    for (int kc = 0; kc < KC; ++kc){
      short8 af0 = *(const short8*)&abuf[lrow * SA + kc * 32 + lq * 8];
      short8 af1 = *(const short8*)&abuf[(16 + lrow) * SA + kc * 32 + lq * 8];
      #pragma unroll
      for (int gt = 0; gt < 4; ++gt){
        short8 bf = WswV[((w * 4 + gt) * KC + kc) * 64 + L];
        acc[gt][0] = mfma16(af0, bf, acc[gt][0]);
        acc[gt][1] = mfma16(af1, bf, acc[gt][1]);
      }
    }
    __syncthreads();                     // all LDS reads of h/x for step t done
    const int col = w * 16 + lrow;
    #pragma unroll
    for (int m0 = 0; m0 < 2; ++m0){
      #pragma unroll
      for (int r = 0; r < 4; ++r){
        const int bm = m0 * 16 + lq * 4 + r;
        const bool mk = t < lenv[m0][r];
        const long gbase = ((long)(b0 + bm) * 200 + t) * 512 + hcol0;
        float gi = acc[0][m0][r] + bv[0];
        float gf = acc[1][m0][r] + bv[1];
        float gg = acc[2][m0][r] + bv[2];
        float go = acc[3][m0][r] + bv[3];
        float cn = fsig(gf) * cst[m0][r] + fsig(gi) * ftanh(gg);
        float hn = fsig(go) * ftanh(cn);
        if (mk){
          cst[m0][r] = cn;
          us16 hb = f2bf(hn);
          abuf[bm * SA + col] = hb;      // state for next step
          hout[gbase + col] = hb;        // masked output = hn
        } else {
          hout[gbase + col] = 0;         // masked output = 0; state kept
        }
      }
    }
    if (tau < 199) load_x(rev ? (198 - tau) : (tau + 1));
    __syncthreads();
  }
}

__global__ __launch_bounds__(1024, 1) void k_lstm(
    const us16* __restrict__ char_vec, const us16* __restrict__ words_bf,
    const us16* __restrict__ wsw_cf, const us16* __restrict__ wsw_cb,
    const us16* __restrict__ wsw_wf, const us16* __restrict__ wsw_wb,
    const float* __restrict__ b_cf, const float* __restrict__ b_cb,
    const float* __restrict__ b_wf, const float* __restrict__ b_wb,
    const int* __restrict__ len_char, const int* __restrict__ len_word,
    us16* __restrict__ h_char, us16* __restrict__ h_word)
{
  const int dir   = blockIdx.x >> 3;
  const int slice = blockIdx.x & 7;
  const bool rev  = dir & 1;
  const int b0 = slice * 32;
  __shared__ us16 abuf[32 * 392];        // [32 rows][SA]: cols 0..255 h, 256.. x

  if (dir < 2){
    lstm_body<9, 32, 296>(abuf, char_vec, dir ? wsw_cb : wsw_cf,
                          dir ? b_cb : b_cf, len_char, h_char,
                          b0, rev ? 256 : 0, rev);
  } else {
    lstm_body<12, 128, 392>(abuf, words_bf, (dir == 3) ? wsw_wb : wsw_wf,
                            (dir == 3) ? b_wb : b_wf, len_word, h_word,
                            b0, rev ? 256 : 0, rev);
  }
}

// ---------- generic FF GEMM: out = softplus(A[M,K]bf16 @ Wsw^T + bias) ----------
__global__ __launch_bounds__(256) void k_gemm(
    const us16* __restrict__ A, int KC, const us16* __restrict__ Wsw,
    const float* __restrict__ bias, int N,
    void* __restrict__ outp, int ostride, int ocol0, int out_f32)
{
  const int tid = threadIdx.x;
  const int w = tid >> 6, L = tid & 63;
  const int lrow = L & 15, lq = L >> 4;
  const int m0base = blockIdx.x * 128;
  const int ntbase = blockIdx.y * 8;
  const int Kd = KC * 32;
  __shared__ us16 At[128 * 40];            // 20 dw stride -> <=2-way banks
  f32x4 acc[8][2] = {};
  const short8* WswV = (const short8*)Wsw;
  const int srow = tid >> 1, scol = (tid & 1) * 16;

  for (int kc = 0; kc < KC; ++kc){
    const long abase = (long)(m0base + srow) * Kd + kc * 32 + scol;
    short8 v0 = *(const short8*)&A[abase];
    short8 v1 = *(const short8*)&A[abase + 8];
    *(short8*)&At[srow * 40 + scol] = v0;
    *(short8*)&At[srow * 40 + scol + 8] = v1;
    __syncthreads();
    short8 af0 = *(const short8*)&At[(w * 32 + lrow) * 40 + lq * 8];
    short8 af1 = *(const short8*)&At[(w * 32 + 16 + lrow) * 40 + lq * 8];
    #pragma unroll
    for (int nt = 0; nt < 8; ++nt){
      short8 bf = WswV[((ntbase + nt) * KC + kc) * 64 + L];
      acc[nt][0] = mfma16(af0, bf, acc[nt][0]);
      acc[nt][1] = mfma16(af1, bf, acc[nt][1]);
    }
    __syncthreads();
  }
  #pragma unroll
  for (int nt = 0; nt < 8; ++nt){
    const int col = (ntbase + nt) * 16 + lrow;
    if (col >= N) continue;
    const float bvv = bias[col];
    #pragma unroll
    for (int m0 = 0; m0 < 2; ++m0){
      #pragma unroll
      for (int r = 0; r < 4; ++r){
        float v = fsoftplus(acc[nt][m0][r] + bvv);
        const int row = m0base + w * 32 + m0 * 16 + lq * 4 + r;
        if (out_f32) ((float*)outp)[(long)row * ostride + ocol0 + col] = v;
        else         ((us16*)outp)[(long)row * ostride + ocol0 + col] = f2bf(v);
      }
    }
  }
}

// ---------- CRF NLL: one wave per batch row ----------
__global__ void k_crf(const float* __restrict__ logits, const int* __restrict__ tags,
                      const int* __restrict__ lens, const float* __restrict__ trans,
                      float* __restrict__ nll)
{
  const int b = blockIdx.x;
  const int lane = threadIdx.x;            // 64
  __shared__ float alpha[12];
  __shared__ float tmp[12];
  float tcol[12];
  if (lane < 12){
    #pragma unroll
    for (int i = 0; i < 12; ++i) tcol[i] = trans[i * 12 + lane];
    alpha[lane] = 0.0f;
  }
  const int len = lens[b];
  __syncthreads();
  for (int t = 0; t < len; ++t){
    float an = 0.0f;
    if (lane < 12){
      float mx = -3.0e38f;
      #pragma unroll
      for (int i = 0; i < 12; ++i) mx = fmaxf(mx, alpha[i] + tcol[i]);
      float ss = 0.0f;
      #pragma unroll
      for (int i = 0; i < 12; ++i)
        ss += __builtin_amdgcn_exp2f(1.4426950408889634f * (alpha[i] + tcol[i] - mx));
      an = logits[((long)b * 200 + t) * 12 + lane] + mx
         + 0.69314718055994531f * __builtin_amdgcn_logf(ss);
    }
    __syncthreads();
    if (lane < 12) alpha[lane] = an;
    __syncthreads();
  }
  if (lane < 12) tmp[lane] = alpha[lane] + trans[lane * 12 + 11];   // + trans[:,STOP]
  __syncthreads();
  float rs = 0.0f;
  for (int t = lane; t < len; t += 64){
    int tg = tags[b * 200 + t];
    int pv = (t == 0) ? 10 : tags[b * 200 + t - 1];                 // START=10
    rs += logits[((long)b * 200 + t) * 12 + tg] + trans[pv * 12 + tg];
  }
  #pragma unroll
  for (int off = 32; off > 0; off >>= 1) rs += __shfl_down(rs, off, 64);
  if (lane == 0){
    float mx = -3.0e38f;
    for (int i = 0; i < 12; ++i) mx = fmaxf(mx, tmp[i]);
    float ss = 0.0f;
    for (int i = 0; i < 12; ++i)
      ss += __builtin_amdgcn_exp2f(1.4426950408889634f * (tmp[i] - mx));
    float total = mx + 0.69314718055994531f * __builtin_amdgcn_logf(ss);
    rs += trans[tags[b * 200 + len - 1] * 12 + 11];                 // trans[last, STOP]
    nll[b] = total - rs;
  }
}

__global__ void k_sum(const float* __restrict__ nll, float* __restrict__ out){
  __shared__ float red[256];
  int t = threadIdx.x;
  red[t] = nll[t];
  __syncthreads();
  for (int s = 128; s > 0; s >>= 1){
    if (t < s) red[t] += red[t + s];
    __syncthreads();
  }
  if (t == 0) out[0] = red[0];
}

// ---------- launcher ----------
extern "C" void kernel_launch(void* const* d_in, const int* in_sizes, int n_in,
                              void* d_out, int out_size, void* d_ws, size_t ws_size,
                              hipStream_t stream)
{
  (void)in_sizes; (void)n_in; (void)out_size; (void)ws_size;
  const int*   characters = (const int*)  d_in[0];
  const float* words      = (const float*)d_in[1];
  const int*   tags       = (const int*)  d_in[2];
  const int*   len_char   = (const int*)  d_in[3];
  const int*   len_word   = (const int*)  d_in[4];
  const float* char_emb   = (const float*)d_in[5];
  const float* char_Wih_f = (const float*)d_in[6];
  const float* char_Whh_f = (const float*)d_in[7];
  const float* char_b_f   = (const float*)d_in[8];
  const float* char_Wih_b = (const float*)d_in[9];
  const float* char_Whh_b = (const float*)d_in[10];
  const float* char_b_b   = (const float*)d_in[11];
  const float* char_lin_W = (const float*)d_in[12];
  const float* char_lin_b = (const float*)d_in[13];
  const float* word_Wih_f = (const float*)d_in[14];
  const float* word_Whh_f = (const float*)d_in[15];
  const float* word_b_f   = (const float*)d_in[16];
  const float* word_Wih_b = (const float*)d_in[17];
  const float* word_Whh_b = (const float*)d_in[18];
  const float* word_b_b   = (const float*)d_in[19];
  const float* word_lin_W = (const float*)d_in[20];
  const float* word_lin_b = (const float*)d_in[21];
  const float* lin1_W     = (const float*)d_in[22];
  const float* lin1_b     = (const float*)d_in[23];
  const float* lin2_W     = (const float*)d_in[24];
  const float* lin2_b     = (const float*)d_in[25];
  const float* tag_W      = (const float*)d_in[26];
  const float* tag_b      = (const float*)d_in[27];
  const float* trans      = (const float*)d_in[28];

  char* ws = (char*)d_ws;
  size_t off = 0;
  auto take = [&](size_t bytes) -> char* {
    char* p = ws + off;
    off = (off + bytes + 511) & ~(size_t)511;
    return p;
  };
  us16* char_vec = (us16*)take((size_t)256*200*32*2);      //  3.1 MB
  us16* words_bf = (us16*)take((size_t)256*200*128*2);     // 12.5 MB
  us16* h_char   = (us16*)take((size_t)51200*512*2);       // 50 MB
  us16* h_word   = (us16*)take((size_t)51200*512*2);       // 50 MB
  us16* x_cat    = (us16*)take((size_t)51200*736*2);       // 71.9 MB
  us16* wsw_cf   = (us16*)take((size_t)64*9*512*2);
  us16* wsw_cb   = (us16*)take((size_t)64*9*512*2);
  us16* wsw_wf   = (us16*)take((size_t)64*12*512*2);
  us16* wsw_wb   = (us16*)take((size_t)64*12*512*2);
  us16* wswg1    = (us16*)take((size_t)32*16*512*2);
  us16* wswg2    = (us16*)take((size_t)16*16*512*2);
  us16* wswg3    = (us16*)take((size_t)32*23*512*2);
  us16* wswg4    = (us16*)take((size_t)16*16*512*2);
  us16* wswg5    = (us16*)take((size_t)8*8*512*2);
  float* logits  = (float*)take((size_t)51200*12*4);
  float* nll     = (float*)take((size_t)256*4);
  us16* x1 = h_char;   // dead after G1
  us16* x2 = h_word;   // dead after G2

  // preprocessing
  k_embed<<<6400, 256, 0, stream>>>(characters, char_emb, char_vec);
  k_cvt<<<(256*200*128 + 255)/256, 256, 0, stream>>>(words, words_bf, 256*200*128);
  k_swz_lstm<<<(64*9*512 + 255)/256, 256, 0, stream>>>(char_Whh_f, char_Wih_f, 30, 9, wsw_cf);
  k_swz_lstm<<<(64*9*512 + 255)/256, 256, 0, stream>>>(char_Whh_b, char_Wih_b, 30, 9, wsw_cb);
  k_swz_lstm<<<(64*12*512 + 255)/256, 256, 0, stream>>>(word_Whh_f, word_Wih_f, 128, 12, wsw_wf);
  k_swz_lstm<<<(64*12*512 + 255)/256, 256, 0, stream>>>(word_Whh_b, word_Wih_b, 128, 12, wsw_wb);
  k_swz_ff<<<(32*16*512 + 255)/256, 256, 0, stream>>>(char_lin_W, 512, 512, 16, wswg1, 32*16*512);
  k_swz_ff<<<(16*16*512 + 255)/256, 256, 0, stream>>>(word_lin_W, 200, 512, 16, wswg2, 16*16*512);
  k_swz_ff<<<(32*23*512 + 255)/256, 256, 0, stream>>>(lin1_W, 512, 712, 23, wswg3, 32*23*512);
  k_swz_ff<<<(16*16*512 + 255)/256, 256, 0, stream>>>(lin2_W, 256, 512, 16, wswg4, 16*16*512);
  k_swz_ff<<<(8*8*512 + 255)/256, 256, 0, stream>>>(tag_W, 12, 256, 8, wswg5, 8*8*512);
  k_zpad<<<4800, 256, 0, stream>>>(x_cat);

  // recurrences (4 directions concurrent in one launch; 16 waves/block)
  k_lstm<<<32, 1024, 0, stream>>>(char_vec, words_bf, wsw_cf, wsw_cb, wsw_wf, wsw_wb,
                                  char_b_f, char_b_b, word_b_f, word_b_b,
                                  len_char, len_word, h_char, h_word);

  // feed-forward chain
  k_gemm<<<dim3(400, 4), 256, 0, stream>>>(h_char, 16, wswg1, char_lin_b, 512, x_cat, 736,   0, 0);
  k_gemm<<<dim3(400, 2), 256, 0, stream>>>(h_word, 16, wswg2, word_lin_b, 200, x_cat, 736, 512, 0);
  k_gemm<<<dim3(400, 4), 256, 0, stream>>>(x_cat, 23, wswg3, lin1_b, 512, x1, 512, 0, 0);
  k_gemm<<<dim3(400, 2), 256, 0, stream>>>(x1,    16, wswg4, lin2_b, 256, x2, 256, 0, 0);
  k_gemm<<<dim3(400, 1), 256, 0, stream>>>(x2,     8, wswg5, tag_b,   12, logits, 12, 0, 1);

  // CRF
  k_crf<<<256, 64, 0, stream>>>(logits, tags, len_char, trans, nll);
  k_sum<<<1, 256, 0, stream>>>(nll, (float*)d_out);
}